// Round 11
// baseline (567.787 us; speedup 1.0000x reference)
//
#include <hip/hip_runtime.h>
#include <cstdint>
#include <cstddef>

#define BB 4
#define NN 4096
#define DD 768
#define EE 2304      // 3*DD
#define MTOT 16384   // BB*NN
static constexpr float ATT_SCALE = 0.03608439182435161f;  // 1/sqrt(768)

typedef _Float16 v8h __attribute__((ext_vector_type(8)));
typedef _Float16 v4h __attribute__((ext_vector_type(4)));
typedef float v4f __attribute__((ext_vector_type(4)));
typedef uint32_t v4u __attribute__((ext_vector_type(4)));

#define LGKM0 asm volatile("s_waitcnt lgkmcnt(0)" ::: "memory")
#define SCHED0 __builtin_amdgcn_sched_barrier(0)
#define BAR __builtin_amdgcn_s_barrier()

enum { EPI_QKV = 0, EPI_F16 = 1, EPI_OUT = 2, EPI_PV = 3 };

// C[M,N] = A[M,K] @ Bt[N,K]^T.  A row-major (lda), Bt n-major (ldb).
// 256x256 tile, BK=64, 512 threads = 8 waves (2x4), per-wave 128x64 output.
//
// ROUND-11: byte-identical RESUBMISSION of R5 (the session's best total,
// 525.1 us).  R8-R10 decomposition left two irreconcilable readings: either
// R5's config is genuinely ~20 us faster than the V^T-fusion bundle, or
// R5's 525 was cross-container variance (R2/R9/R10 all ~544-545).  This
// re-measurement resolves it; pre-committed: ~525 -> keep R5 config (real);
// ~540-550 -> 525 was noise, plateau is ~545, declare next round.
//
// Register-staged staging (T14/HK-style): per K-tile per thread:
//   8 x global_load_dwordx4 -> 32 VGPRs  (issued at END of iter t for tile
//   t+2: ~1 full K-tile of latency slack; compiler's automatic counted
//   vmcnt before first register use never drains to 0 mid-loop)
//   8 x ds_write_b128 into slot ns       (after ALL of tile t's ds_reads,
//   so no LDS may-alias stall; lgkmcnt(0)+barrier publishes before t+1)
//
// LDS: 2 slots x {A,B} x [256 rows][64 elems] (32 KB each) = 128 KB.
// Swizzle (proven 0-conflict read pattern): row r, physical 16B-chunk
// pc = kc ^ (r&7) — applied on the ds_write ADDRESS.  ks1 fragment offsets
// = ks0 offsets ^ 32 elems (chunk bit2 flip; row term has only bits >=6).
//
// SWZ=1 (QK^T only; requires gx==16, gy==16): XCD x owns an 8x4 block
// supertile -> co-resident L2 working set ~4.7 MB.
//
// EPI_PV: blockIdx.z = khalf*2 + batch; k-range [khalf*K, khalf*K+K);
//         C = c_f32 + khalf*chalf + batch*zC (plain f32 partial stores).
// Other EPIs: blockIdx.z = batch (offsets zA/zB/zC).
template <int EPI, int SWZ = 0>
__global__ __launch_bounds__(512, 2) void gemm256(
    const _Float16* __restrict__ A, int lda, size_t zA,
    const _Float16* __restrict__ Bt, int ldb, size_t zB,
    int K,
    float* __restrict__ c_f32,
    _Float16* __restrict__ c_f16,
    int ldc, size_t zC, size_t chalf,
    const float* __restrict__ bias,
    _Float16* __restrict__ q_out,
    _Float16* __restrict__ k_out,
    _Float16* __restrict__ v_out) {
  __shared__ __align__(16) _Float16 As[2][256 * 64];
  __shared__ __align__(16) _Float16 Bs[2][256 * 64];

  const int tid = threadIdx.x;
  const int wid = tid >> 6, lane = tid & 63;
  const int wr = wid >> 2, wc = wid & 3;       // wave grid 2x4 (128x64 each)
  const int lq = lane >> 4, lr = lane & 15;    // quad, row-in-tile

  int bx = blockIdx.x, by = blockIdx.y;
  if constexpr (SWZ == 1) {
    // Valid for gx=16, gy=16: bijective (xcd,j) -> 8x4 supertile coords.
    const int lin = bx + (by << 4);
    const int xcd = lin & 7, j = lin >> 3;  // j in [0,32)
    bx = (xcd & 1) * 8 + (j & 7);
    by = (xcd >> 1) * 4 + (j >> 3);
  }
  const int m0 = bx * 256, n0 = by * 256;
  const int z = blockIdx.z;
  int bidx, koff;
  if constexpr (EPI == EPI_PV) {
    bidx = z & 1;            // batch within chunk
    koff = (z >> 1) * K;     // k-half offset
  } else {
    bidx = z;
    koff = 0;
  }

  const _Float16* Ab = A + (size_t)bidx * zA + (size_t)m0 * lda + koff;
  const _Float16* Bb = Bt + (size_t)bidx * zB + (size_t)n0 * ldb + koff;

  // Staging map: 2048 16B-chunks per matrix per K-tile, 4 per thread.
  // chunk c = i*512+tid: row r = c>>3, logical k-chunk kc = c&7.
  // gmem: linear (r, kc); LDS: physical chunk pc = kc ^ (r&7).
  int gA[4], gB[4], lds_off[4];
#pragma unroll
  for (int i = 0; i < 4; ++i) {
    const int c = i * 512 + tid;
    const int r = c >> 3, kc = c & 7;
    gA[i] = r * lda + kc * 8;
    gB[i] = r * ldb + kc * 8;
    lds_off[i] = r * 64 + ((kc ^ (r & 7)) << 3);
  }

  // Fragment read offsets (elems), ks=0; ks=1 is ^32.
  int aoff[8], boff[4];
#pragma unroll
  for (int t = 0; t < 8; ++t) {
    const int ra = wr * 128 + t * 16 + lr;
    aoff[t] = ra * 64 + ((lq ^ (ra & 7)) << 3);
  }
#pragma unroll
  for (int n = 0; n < 4; ++n) {
    const int rb = wc * 64 + n * 16 + lr;
    boff[n] = rb * 64 + ((lq ^ (rb & 7)) << 3);
  }

  v4f acc[8][4] = {};
  const int NT = K / 64;  // all call sites: NT >= 6

  v4u va[4], vb[4];  // in-flight staging registers (32 VGPR)

  auto loadT = [&](int kt) {
    const _Float16* a = Ab + kt * 64;
    const _Float16* b = Bb + kt * 64;
#pragma unroll
    for (int i = 0; i < 4; ++i) {
      va[i] = *(const v4u*)(a + gA[i]);
      vb[i] = *(const v4u*)(b + gB[i]);
    }
  };
  auto writeT = [&](int slot) {
#pragma unroll
    for (int i = 0; i < 4; ++i) {
      *(v4u*)(&As[slot][0] + lds_off[i]) = va[i];
      *(v4u*)(&Bs[slot][0] + lds_off[i]) = vb[i];
    }
  };
  auto mfma16 = [&](const v8h* af_, const v8h* bf_, int mbase) {
#pragma unroll
    for (int mt = 0; mt < 4; ++mt)
#pragma unroll
      for (int nt = 0; nt < 4; ++nt)
        acc[mbase + mt][nt] = __builtin_amdgcn_mfma_f32_16x16x32_f16(
            af_[mt], bf_[nt], acc[mbase + mt][nt], 0, 0, 0);
  };

  // Prologue: tile 0 -> regs -> slot 0; issue tile 1 loads; publish.
  loadT(0);
  writeT(0);
  loadT(1);
  LGKM0;
  SCHED0;
  BAR;
  SCHED0;

  for (int t = 0; t < NT; ++t) {
    const int cur = t & 1, ns = cur ^ 1;
    const _Float16* Ac = &As[cur][0];
    const _Float16* Bc = &Bs[cur][0];
    v8h a_[4], b0_[4], b1_[4];

    // ---- phase 0: ks0, mt 0-3 ----
#pragma unroll
    for (int i = 0; i < 4; ++i) a_[i] = *(const v8h*)(Ac + aoff[i]);
#pragma unroll
    for (int i = 0; i < 4; ++i) b0_[i] = *(const v8h*)(Bc + boff[i]);
    __builtin_amdgcn_s_setprio(1);
    mfma16(a_, b0_, 0);
    __builtin_amdgcn_s_setprio(0);

    // ---- phase 1: ks0, mt 4-7 (b0_ live) ----
#pragma unroll
    for (int i = 0; i < 4; ++i) a_[i] = *(const v8h*)(Ac + aoff[4 + i]);
    __builtin_amdgcn_s_setprio(1);
    mfma16(a_, b0_, 4);
    __builtin_amdgcn_s_setprio(0);

    // ---- phase 2: ks1, mt 0-3 ----
#pragma unroll
    for (int i = 0; i < 4; ++i) a_[i] = *(const v8h*)(Ac + (aoff[i] ^ 32));
#pragma unroll
    for (int i = 0; i < 4; ++i) b1_[i] = *(const v8h*)(Bc + (boff[i] ^ 32));
    __builtin_amdgcn_s_setprio(1);
    mfma16(a_, b1_, 0);
    __builtin_amdgcn_s_setprio(0);

    // ---- phase 3: ks1, mt 4-7 ----
#pragma unroll
    for (int i = 0; i < 4; ++i) a_[i] = *(const v8h*)(Ac + (aoff[4 + i] ^ 32));
    __builtin_amdgcn_s_setprio(1);
    mfma16(a_, b1_, 4);
    __builtin_amdgcn_s_setprio(0);

    // ---- stage tail: all reads of slot cur are done above ----
    if (t + 1 < NT) {
      writeT(ns);                    // regs (tile t+1) -> LDS; compiler's
      if (t + 2 < NT) loadT(t + 2);  // counted vmcnt; then reissue loads
    }
    LGKM0;   // ds_writes + ds_reads drained before any wave crosses
    SCHED0;
    BAR;
    SCHED0;
  }

  // Epilogue. C/D frag: col = lane&15, row = (lane>>4)*4 + reg (m89/m91).
  float* cf = nullptr;
  _Float16* ch = nullptr;
  if constexpr (EPI == EPI_PV)
    cf = c_f32 + (size_t)(z >> 1) * chalf + (size_t)bidx * zC;
  else if constexpr (EPI == EPI_OUT)
    cf = c_f32 + (size_t)bidx * zC;
  else if constexpr (EPI == EPI_F16)
    ch = c_f16 + (size_t)bidx * zC;

#pragma unroll
  for (int mt = 0; mt < 8; ++mt) {
#pragma unroll
    for (int nt = 0; nt < 4; ++nt) {
#pragma unroll
      for (int rg = 0; rg < 4; ++rg) {
        const int gm = m0 + wr * 128 + mt * 16 + lq * 4 + rg;
        const int gn = n0 + wc * 64 + nt * 16 + lr;
        float v = acc[mt][nt][rg];
        if constexpr (EPI == EPI_QKV) {
          v += bias[gn];
          if (gn < DD) {            // uniform per 16-wide run (768 % 16 == 0)
            q_out[(size_t)gm * DD + gn] = (_Float16)(v * ATT_SCALE);
          } else if (gn < 2 * DD) {
            k_out[(size_t)gm * DD + (gn - DD)] = (_Float16)v;
          } else {
            v_out[(size_t)gm * DD + (gn - 2 * DD)] = (_Float16)v;
          }
        } else if constexpr (EPI == EPI_F16) {
          ch[(size_t)gm * ldc + gn] = (_Float16)v;
        } else {  // EPI_PV / EPI_OUT
          cf[(size_t)gm * ldc + gn] = (EPI == EPI_OUT) ? v + bias[gn] : v;
        }
      }
    }
  }
}

// ctx f16 = half0 + half1 (split-K reduce + f32->f16 convert).
__global__ __launch_bounds__(256) void reduce_ctx(const float* __restrict__ h0,
                                                  const float* __restrict__ h1,
                                                  _Float16* __restrict__ out,
                                                  int n4) {
  int i = blockIdx.x * blockDim.x + threadIdx.x;
  if (i < n4) {
    v4f a = ((const v4f*)h0)[i];
    v4f b = ((const v4f*)h1)[i];
    v4h o;
#pragma unroll
    for (int j = 0; j < 4; ++j) o[j] = (_Float16)(a[j] + b[j]);
    ((v4h*)out)[i] = o;
  }
}

// Row softmax over f16 scores, in place. Grid (NN, nz); one block per row.
__global__ __launch_bounds__(256) void softmax_rows_f16(_Float16* __restrict__ S) {
  _Float16* row = S + (size_t)blockIdx.y * NN * NN + (size_t)blockIdx.x * NN;
  const int tid = threadIdx.x;
  const int lane = tid & 63, wid = tid >> 6;

  float f[16];
  float m = -3.0e38f;
#pragma unroll
  for (int i = 0; i < 2; ++i) {
    v8h v = ((const v8h*)row)[tid + i * 256];
#pragma unroll
    for (int j = 0; j < 8; ++j) {
      f[i * 8 + j] = (float)v[j];
      m = fmaxf(m, f[i * 8 + j]);
    }
  }
#pragma unroll
  for (int off = 32; off > 0; off >>= 1) m = fmaxf(m, __shfl_xor(m, off));
  __shared__ float redm[4], reds[4];
  if (lane == 0) redm[wid] = m;
  __syncthreads();
  m = fmaxf(fmaxf(redm[0], redm[1]), fmaxf(redm[2], redm[3]));

  float sum = 0.f;
#pragma unroll
  for (int i = 0; i < 16; ++i) {
    f[i] = __expf(f[i] - m);
    sum += f[i];
  }
#pragma unroll
  for (int off = 32; off > 0; off >>= 1) sum += __shfl_xor(sum, off);
  if (lane == 0) reds[wid] = sum;
  __syncthreads();
  sum = reds[0] + reds[1] + reds[2] + reds[3];
  const float inv = 1.0f / sum;
#pragma unroll
  for (int i = 0; i < 2; ++i) {
    v8h o;
#pragma unroll
    for (int j = 0; j < 8; ++j) o[j] = (_Float16)(f[i * 8 + j] * inv);
    ((v8h*)row)[tid + i * 256] = o;
  }
}

__global__ __launch_bounds__(256) void cvt_f16(const float* __restrict__ in,
                                               _Float16* __restrict__ out, int n4) {
  int i = blockIdx.x * blockDim.x + threadIdx.x;
  if (i < n4) {
    v4f v = ((const v4f*)in)[i];
    v4h o;
#pragma unroll
    for (int j = 0; j < 4; ++j) o[j] = (_Float16)v[j];
    ((v4h*)out)[i] = o;
  }
}

// out[C][R] (f16) = in[R][C] (f32). Grid (C/32, R/32), 256 threads (32x8).
__global__ __launch_bounds__(256) void transpose_cvt(const float* __restrict__ in,
                                                     _Float16* __restrict__ out,
                                                     int R, int C) {
  __shared__ float tile[32][33];
  const int bx = blockIdx.x * 32;  // C base
  const int by = blockIdx.y * 32;  // R base
  const int tx = threadIdx.x & 31, ty = threadIdx.x >> 5;
#pragma unroll
  for (int i = 0; i < 32; i += 8)
    tile[ty + i][tx] = in[(size_t)(by + ty + i) * C + (bx + tx)];
  __syncthreads();
#pragma unroll
  for (int i = 0; i < 32; i += 8)
    out[(size_t)(bx + ty + i) * R + (by + tx)] = (_Float16)tile[tx][ty + i];
}

// Vt[b][d][n] = V[b][n][d], f16. Grid (DD/32, NN/32, BB).
__global__ __launch_bounds__(256) void transpose_v(const _Float16* __restrict__ in,
                                                   _Float16* __restrict__ out) {
  __shared__ _Float16 tile[32][33];
  const int b = blockIdx.z;
  const _Float16* src = in + (size_t)b * NN * DD;
  _Float16* dst = out + (size_t)b * NN * DD;
  const int bx = blockIdx.x * 32;  // DD base
  const int by = blockIdx.y * 32;  // NN base
  const int tx = threadIdx.x & 31, ty = threadIdx.x >> 5;
#pragma unroll
  for (int i = 0; i < 32; i += 8)
    tile[ty + i][tx] = src[(size_t)(by + ty + i) * DD + (bx + tx)];
  __syncthreads();
#pragma unroll
  for (int i = 0; i < 32; i += 8)
    dst[(size_t)(bx + ty + i) * NN + (by + tx)] = tile[tx][ty + i];
}

extern "C" void kernel_launch(void* const* d_in, const int* in_sizes, int n_in,
                              void* d_out, int out_size, void* d_ws, size_t ws_size,
                              hipStream_t stream) {
  const float* x = (const float*)d_in[0];      // [16384][768]
  const float* w_qkv = (const float*)d_in[1];  // [768][2304]
  const float* b_qkv = (const float*)d_in[2];  // [2304]
  const float* w_out = (const float*)d_in[3];  // [768][768]
  const float* b_out = (const float*)d_in[4];  // [768]
  float* out = (float*)d_out;                  // [16384][768] — also used as
                                               // split-K f32 partial scratch
  char* ws = (char*)d_ws;

  // ws layout, peak 164.5 MB (proven in prior rounds):
  _Float16* xh    = (_Float16*)(ws + 0);           // 25 MB  (dead after QKV gemm)
  _Float16* wqkvh = (_Float16*)(ws + 25165824);    // 3.5 MB [2304][768] = W^T
  _Float16* wouth = (_Float16*)(ws + 28704768);    // 1.2 MB [768][768]  = Wout^T
  _Float16* Qh    = (_Float16*)(ws + 29884416);    // 25 MB  (pre-scaled)
  _Float16* Kh    = (_Float16*)(ws + 55050240);    // 25 MB
  _Float16* Vh    = (_Float16*)(ws + 80216064);    // 25 MB  (dead after transpose)
  _Float16* Sh    = (_Float16*)(ws + 105381888);   // 64 MB  f16 scores, 2 batches
  _Float16* Vth   = (_Float16*)(ws + 0);           // reuse xh: [4][768][4096]
  _Float16* Ch    = (_Float16*)(ws + 80216064);    // reuse Vh: [16384][768] ctx

  const size_t zQK = (size_t)NN * DD;   // per-batch stride Q/K/Vt/C (f16 elems)
  const size_t zS = (size_t)NN * NN;    // per-batch stride S (f16 elems)
  const size_t zCtx = (size_t)NN * DD;  // per-batch stride ctx partial (f32)
  const size_t chalf = 2 * zCtx;        // k-half stride in d_out (f32 elems)

  // 1) precision converts / weight transposes
  cvt_f16<<<dim3((MTOT * DD / 4) / 256), 256, 0, stream>>>(x, xh, MTOT * DD / 4);
  transpose_cvt<<<dim3(EE / 32, DD / 32), 256, 0, stream>>>(w_qkv, wqkvh, DD, EE);
  transpose_cvt<<<dim3(DD / 32, DD / 32), 256, 0, stream>>>(w_out, wouth, DD, DD);

  // 2) fused QKV projection (scale folded into Q): grid (64, 9)
  gemm256<EPI_QKV><<<dim3(MTOT / 256, EE / 256), 512, 0, stream>>>(
      xh, DD, 0, wqkvh, DD, 0, DD, nullptr, nullptr, 0, 0, 0, b_qkv, Qh, Kh, Vh);

  // 3) V -> V^T for the PV gemm's n-major B operand
  transpose_v<<<dim3(DD / 32, NN / 32, BB), 256, 0, stream>>>(Vh, Vth);

  // 4) attention in 2-batch chunks: S=QK^T (f16) ; softmax ; ctx=PV split-K=2
  //    PV partials: plain f32 stores into the two halves of d_out (50.3 MB =
  //    exactly 2 halves x 2 batches x 4096 x 768 f32), then reduce to Ch f16.
  for (int c = 0; c < BB / 2; ++c) {
    const _Float16* Qc = Qh + (size_t)c * 2 * zQK;
    const _Float16* Kc = Kh + (size_t)c * 2 * zQK;
    const _Float16* Vtc = Vth + (size_t)c * 2 * zQK;
    gemm256<EPI_F16, 1><<<dim3(NN / 256, NN / 256, 2), 512, 0, stream>>>(
        Qc, DD, zQK, Kc, DD, zQK, DD, nullptr, Sh, NN, zS, 0, nullptr, nullptr,
        nullptr, nullptr);
    softmax_rows_f16<<<dim3(NN, 2), 256, 0, stream>>>(Sh);
    gemm256<EPI_PV><<<dim3(NN / 256, DD / 256, 4), 512, 0, stream>>>(
        Sh, NN, zS, Vtc, NN, zQK, NN / 2, out, nullptr, DD, zCtx, chalf,
        nullptr, nullptr, nullptr, nullptr);
    reduce_ctx<<<dim3((int)(chalf / 4 / 256)), 256, 0, stream>>>(
        out, out + chalf, Ch + (size_t)c * 2 * zQK, (int)(chalf / 4));
  }

  // 5) output projection (reads Ch f16; overwrites d_out with final f32+bias)
  gemm256<EPI_OUT><<<dim3(MTOT / 256, DD / 256), 512, 0, stream>>>(
      Ch, DD, 0, wouth, DD, 0, DD, out, nullptr, DD, 0, 0, b_out, nullptr,
      nullptr, nullptr);
}

// Round 12
// 521.811 us; speedup vs baseline: 1.0881x; 1.0881x over previous
//
#include <hip/hip_runtime.h>
#include <cstdint>
#include <cstddef>

#define BB 4
#define NN 4096
#define DD 768
#define EE 2304      // 3*DD
#define MTOT 16384   // BB*NN
static constexpr float ATT_SCALE = 0.03608439182435161f;  // 1/sqrt(768)

typedef _Float16 v8h __attribute__((ext_vector_type(8)));
typedef _Float16 v4h __attribute__((ext_vector_type(4)));
typedef float v4f __attribute__((ext_vector_type(4)));
typedef uint32_t v4u __attribute__((ext_vector_type(4)));

#define LGKM0 asm volatile("s_waitcnt lgkmcnt(0)" ::: "memory")
#define SCHED0 __builtin_amdgcn_sched_barrier(0)
#define BAR __builtin_amdgcn_s_barrier()

enum { EPI_QKV = 0, EPI_QKT = 1, EPI_OUT = 2, EPI_PV = 3 };

// FINAL (R12 = R10 byte-identical).  Session conclusion:
//  - Cross-container total noise is +-20-25 us (R5's binary: 525 then 568);
//    only within-run dispatch deltas are trustworthy.
//  - Within-run verified wins kept here: (1) QKV staged f16 epilogue with
//    direct V^T write (QKV dispatch 104->94 us, reproduced R8+R9);
//    (2) transpose_v pass deleted (-10 us of dispatch time).
//  - Verified nulls/negatives (reverted): QKT staged epilogue, PV/OUT staged
//    f32 epilogue, all K-loop schedule variants (R1-R3), global_load_lds vs
//    reg staging (R5 A/B), occupancy pinning (R4), softmax fusion (R6).
//  - Structural plateau: the gemm core runs ~590 TF (MfmaUtil ~23%) across
//    every schedule/staging/tile permutation tried; no pipe saturated.
//
// C[M,N] = A[M,K] @ Bt[N,K]^T.  A row-major (lda), Bt n-major (ldb).
// 256x256 tile, BK=64, 512 threads = 8 waves (2x4), per-wave 128x64 output.
// Register-staged K-loop (R5 structure): per K-tile, 8 global_load_dwordx4
// -> 32 VGPR (issued 2 tiles ahead) then 8 ds_write_b128 after all of the
// current tile's ds_reads; one lgkmcnt(0)+barrier per tile.
//
// LDS: one SMEM[65536] f16 buffer.  K-loop: A slot s = SMEM+s*16384,
// B slot s = SMEM+32768+s*16384.  Swizzle: row r, physical 16B-chunk
// pc = kc ^ (r&7), applied on the ds_write address; reads mirror it
// (0-conflict proven).  ks1 fragment offsets = ks0 ^ 32 elems.
//
// SWZ=1 (QKT only; requires gx==16, gy==16): XCD x owns an 8x4 block
// supertile -> co-resident L2 working set ~4.7 MB.
//
// EPI_PV: blockIdx.z = khalf*2 + batch; k-range [khalf*K, khalf*K+K);
//         C = c_f32 + khalf*chalf + batch*zC (plain f32 partial stores).
// Other EPIs: blockIdx.z = batch (offsets zA/zB/zC).
template <int EPI, int SWZ = 0>
__global__ __launch_bounds__(512, 2) void gemm256(
    const _Float16* __restrict__ A, int lda, size_t zA,
    const _Float16* __restrict__ Bt, int ldb, size_t zB,
    int K,
    float* __restrict__ c_f32,
    _Float16* __restrict__ c_f16,
    int ldc, size_t zC, size_t chalf,
    const float* __restrict__ bias,
    _Float16* __restrict__ q_out,
    _Float16* __restrict__ k_out,
    _Float16* __restrict__ v_out) {
  __shared__ __align__(16) _Float16 SMEM[65536];  // 128 KB

  const int tid = threadIdx.x;
  const int wid = tid >> 6, lane = tid & 63;
  const int wr = wid >> 2, wc = wid & 3;       // wave grid 2x4 (128x64 each)
  const int lq = lane >> 4, lr = lane & 15;    // quad, row-in-tile

  int bx = blockIdx.x, by = blockIdx.y;
  if constexpr (SWZ == 1) {
    // Valid for gx=16, gy=16: bijective (xcd,j) -> 8x4 supertile coords.
    const int lin = bx + (by << 4);
    const int xcd = lin & 7, j = lin >> 3;  // j in [0,32)
    bx = (xcd & 1) * 8 + (j & 7);
    by = (xcd >> 1) * 4 + (j >> 3);
  }
  const int m0 = bx * 256, n0 = by * 256;
  const int z = blockIdx.z;
  int bidx, koff;
  if constexpr (EPI == EPI_PV) {
    bidx = z & 1;            // batch within chunk
    koff = (z >> 1) * K;     // k-half offset
  } else {
    bidx = z;
    koff = 0;
  }

  const _Float16* Ab = A + (size_t)bidx * zA + (size_t)m0 * lda + koff;
  const _Float16* Bb = Bt + (size_t)bidx * zB + (size_t)n0 * ldb + koff;

  // Staging map: 2048 16B-chunks per matrix per K-tile, 4 per thread.
  // chunk c = i*512+tid: row r = c>>3, logical k-chunk kc = c&7.
  // gmem: linear (r, kc); LDS: physical chunk pc = kc ^ (r&7).
  int gA[4], gB[4], lds_off[4];
#pragma unroll
  for (int i = 0; i < 4; ++i) {
    const int c = i * 512 + tid;
    const int r = c >> 3, kc = c & 7;
    gA[i] = r * lda + kc * 8;
    gB[i] = r * ldb + kc * 8;
    lds_off[i] = r * 64 + ((kc ^ (r & 7)) << 3);
  }

  // Fragment read offsets (elems), ks=0; ks=1 is ^32.
  int aoff[8], boff[4];
#pragma unroll
  for (int t = 0; t < 8; ++t) {
    const int ra = wr * 128 + t * 16 + lr;
    aoff[t] = ra * 64 + ((lq ^ (ra & 7)) << 3);
  }
#pragma unroll
  for (int n = 0; n < 4; ++n) {
    const int rb = wc * 64 + n * 16 + lr;
    boff[n] = rb * 64 + ((lq ^ (rb & 7)) << 3);
  }

  v4f acc[8][4] = {};
  const int NT = K / 64;  // all call sites: NT >= 6

  v4u va[4], vb[4];  // in-flight staging registers (32 VGPR)

  auto loadT = [&](int kt) {
    const _Float16* a = Ab + kt * 64;
    const _Float16* b = Bb + kt * 64;
#pragma unroll
    for (int i = 0; i < 4; ++i) {
      va[i] = *(const v4u*)(a + gA[i]);
      vb[i] = *(const v4u*)(b + gB[i]);
    }
  };
  auto writeT = [&](int slot) {
    _Float16* As = SMEM + slot * 16384;
    _Float16* Bs = SMEM + 32768 + slot * 16384;
#pragma unroll
    for (int i = 0; i < 4; ++i) {
      *(v4u*)(As + lds_off[i]) = va[i];
      *(v4u*)(Bs + lds_off[i]) = vb[i];
    }
  };
  auto mfma16 = [&](const v8h* af_, const v8h* bf_, int mbase) {
#pragma unroll
    for (int mt = 0; mt < 4; ++mt)
#pragma unroll
      for (int nt = 0; nt < 4; ++nt)
        acc[mbase + mt][nt] = __builtin_amdgcn_mfma_f32_16x16x32_f16(
            af_[mt], bf_[nt], acc[mbase + mt][nt], 0, 0, 0);
  };

  // Prologue: tile 0 -> regs -> slot 0; issue tile 1 loads; publish.
  loadT(0);
  writeT(0);
  loadT(1);
  LGKM0;
  SCHED0;
  BAR;
  SCHED0;

  for (int t = 0; t < NT; ++t) {
    const int cur = t & 1, ns = cur ^ 1;
    const _Float16* Ac = SMEM + cur * 16384;
    const _Float16* Bc = SMEM + 32768 + cur * 16384;
    v8h a_[4], b0_[4], b1_[4];

    // ---- phase 0: ks0, mt 0-3 ----
#pragma unroll
    for (int i = 0; i < 4; ++i) a_[i] = *(const v8h*)(Ac + aoff[i]);
#pragma unroll
    for (int i = 0; i < 4; ++i) b0_[i] = *(const v8h*)(Bc + boff[i]);
    __builtin_amdgcn_s_setprio(1);
    mfma16(a_, b0_, 0);
    __builtin_amdgcn_s_setprio(0);

    // ---- phase 1: ks0, mt 4-7 (b0_ live) ----
#pragma unroll
    for (int i = 0; i < 4; ++i) a_[i] = *(const v8h*)(Ac + aoff[4 + i]);
    __builtin_amdgcn_s_setprio(1);
    mfma16(a_, b0_, 4);
    __builtin_amdgcn_s_setprio(0);

    // ---- phase 2: ks1, mt 0-3 ----
#pragma unroll
    for (int i = 0; i < 4; ++i) a_[i] = *(const v8h*)(Ac + (aoff[i] ^ 32));
#pragma unroll
    for (int i = 0; i < 4; ++i) b1_[i] = *(const v8h*)(Bc + (boff[i] ^ 32));
    __builtin_amdgcn_s_setprio(1);
    mfma16(a_, b1_, 0);
    __builtin_amdgcn_s_setprio(0);

    // ---- phase 3: ks1, mt 4-7 ----
#pragma unroll
    for (int i = 0; i < 4; ++i) a_[i] = *(const v8h*)(Ac + (aoff[4 + i] ^ 32));
    __builtin_amdgcn_s_setprio(1);
    mfma16(a_, b1_, 4);
    __builtin_amdgcn_s_setprio(0);

    // ---- stage tail: all reads of slot cur are done above ----
    if (t + 1 < NT) {
      writeT(ns);                    // regs (tile t+1) -> LDS; compiler's
      if (t + 2 < NT) loadT(t + 2);  // counted vmcnt; then reissue loads
    }
    LGKM0;   // ds_writes + ds_reads drained before any wave crosses
    SCHED0;
    BAR;
    SCHED0;
  }
  // Last barrier of the loop: all LDS ops drained, SMEM is dead. acc live.

  // ======================= epilogues ==========================
  // C/D frag: col = lane&15, row = (lane>>4)*4 + reg (m89/m91).

  if constexpr (EPI == EPI_QKV) {
    // Staged f16 epilogue (measured -11 us in R8 AND R9).
    // Phase 1: stage f16 tile.  V region (by>=6) stages TRANSPOSED.
    // Swizzle: phys f16 col = col ^ ((row&7)<<3)  (16B-chunk XOR).
    const bool vreg = (by >= 6);
    const float scl = (by < 3) ? ATT_SCALE : 1.0f;
#pragma unroll
    for (int mt = 0; mt < 8; ++mt) {
#pragma unroll
      for (int nt = 0; nt < 4; ++nt) {
#pragma unroll
        for (int rg = 0; rg < 4; ++rg) {
          const int rr = wr * 128 + mt * 16 + lq * 4 + rg;
          const int cc = wc * 64 + nt * 16 + lr;
          const float v = (acc[mt][nt][rg] + bias[n0 + cc]) * scl;
          const int row = vreg ? cc : rr;
          const int col = vreg ? rr : cc;
          SMEM[row * 256 + (col ^ ((row & 7) << 3))] = (_Float16)v;
        }
      }
    }
    __syncthreads();
    // Phase 2: 8192 16B-chunks; 32 chunks/row; v8h coalesced stores.
    const int bat = m0 >> 12, mloc = m0 & (NN - 1);
#pragma unroll
    for (int i2 = 0; i2 < 16; ++i2) {
      const int c = i2 * 512 + tid;
      const int row = c >> 5, cic = c & 31;
      v8h val = *(const v8h*)(SMEM + row * 256 + ((cic ^ (row & 7)) << 3));
      if (by < 3) {
        *(v8h*)(q_out + (size_t)(m0 + row) * DD + (n0 + cic * 8)) = val;
      } else if (by < 6) {
        *(v8h*)(k_out + (size_t)(m0 + row) * DD + (n0 - DD + cic * 8)) = val;
      } else {
        // transposed tile: SMEM row = feature d_local, cols = tokens.
        *(v8h*)(v_out + (size_t)bat * NN * DD +
                (size_t)(n0 - 2 * DD + row) * NN + (mloc + cic * 8)) = val;
      }
    }
  } else if constexpr (EPI == EPI_QKT) {
    // Scalar f16 stores (staged version verified null-to-negative, R9/R10).
    _Float16* ch = c_f16 + (size_t)bidx * zC;
#pragma unroll
    for (int mt = 0; mt < 8; ++mt) {
#pragma unroll
      for (int nt = 0; nt < 4; ++nt) {
#pragma unroll
        for (int rg = 0; rg < 4; ++rg) {
          const int gm = m0 + wr * 128 + mt * 16 + lq * 4 + rg;
          const int gn = n0 + wc * 64 + nt * 16 + lr;
          ch[(size_t)gm * ldc + gn] = (_Float16)acc[mt][nt][rg];
        }
      }
    }
  } else {
    // f32 EPIs (PV partials / OUT+bias): direct scalar stores (64B-segment
    // coalesced; staged version verified negative, R8/R9).
    float* cf;
    if constexpr (EPI == EPI_PV)
      cf = c_f32 + (size_t)(z >> 1) * chalf + (size_t)bidx * zC;
    else
      cf = c_f32 + (size_t)bidx * zC;
#pragma unroll
    for (int mt = 0; mt < 8; ++mt) {
#pragma unroll
      for (int nt = 0; nt < 4; ++nt) {
#pragma unroll
        for (int rg = 0; rg < 4; ++rg) {
          const int gm = m0 + wr * 128 + mt * 16 + lq * 4 + rg;
          const int gn = n0 + wc * 64 + nt * 16 + lr;
          float v = acc[mt][nt][rg];
          if constexpr (EPI == EPI_OUT) v += bias[gn];
          cf[(size_t)gm * ldc + gn] = v;
        }
      }
    }
  }
}

// ctx f16 = half0 + half1 (split-K reduce + f32->f16 convert).
__global__ __launch_bounds__(256) void reduce_ctx(const float* __restrict__ h0,
                                                  const float* __restrict__ h1,
                                                  _Float16* __restrict__ out,
                                                  int n4) {
  int i = blockIdx.x * blockDim.x + threadIdx.x;
  if (i < n4) {
    v4f a = ((const v4f*)h0)[i];
    v4f b = ((const v4f*)h1)[i];
    v4h o;
#pragma unroll
    for (int j = 0; j < 4; ++j) o[j] = (_Float16)(a[j] + b[j]);
    ((v4h*)out)[i] = o;
  }
}

// Row softmax over f16 scores, in place. Grid (NN, nz); one block per row.
__global__ __launch_bounds__(256) void softmax_rows_f16(_Float16* __restrict__ S) {
  _Float16* row = S + (size_t)blockIdx.y * NN * NN + (size_t)blockIdx.x * NN;
  const int tid = threadIdx.x;
  const int lane = tid & 63, wid = tid >> 6;

  float f[16];
  float m = -3.0e38f;
#pragma unroll
  for (int i = 0; i < 2; ++i) {
    v8h v = ((const v8h*)row)[tid + i * 256];
#pragma unroll
    for (int j = 0; j < 8; ++j) {
      f[i * 8 + j] = (float)v[j];
      m = fmaxf(m, f[i * 8 + j]);
    }
  }
#pragma unroll
  for (int off = 32; off > 0; off >>= 1) m = fmaxf(m, __shfl_xor(m, off));
  __shared__ float redm[4], reds[4];
  if (lane == 0) redm[wid] = m;
  __syncthreads();
  m = fmaxf(fmaxf(redm[0], redm[1]), fmaxf(redm[2], redm[3]));

  float sum = 0.f;
#pragma unroll
  for (int i = 0; i < 16; ++i) {
    f[i] = __expf(f[i] - m);
    sum += f[i];
  }
#pragma unroll
  for (int off = 32; off > 0; off >>= 1) sum += __shfl_xor(sum, off);
  if (lane == 0) reds[wid] = sum;
  __syncthreads();
  sum = reds[0] + reds[1] + reds[2] + reds[3];
  const float inv = 1.0f / sum;
#pragma unroll
  for (int i = 0; i < 2; ++i) {
    v8h o;
#pragma unroll
    for (int j = 0; j < 8; ++j) o[j] = (_Float16)(f[i * 8 + j] * inv);
    ((v8h*)row)[tid + i * 256] = o;
  }
}

__global__ __launch_bounds__(256) void cvt_f16(const float* __restrict__ in,
                                               _Float16* __restrict__ out, int n4) {
  int i = blockIdx.x * blockDim.x + threadIdx.x;
  if (i < n4) {
    v4f v = ((const v4f*)in)[i];
    v4h o;
#pragma unroll
    for (int j = 0; j < 4; ++j) o[j] = (_Float16)v[j];
    ((v4h*)out)[i] = o;
  }
}

// out[C][R] (f16) = in[R][C] (f32). Grid (C/32, R/32), 256 threads (32x8).
__global__ __launch_bounds__(256) void transpose_cvt(const float* __restrict__ in,
                                                     _Float16* __restrict__ out,
                                                     int R, int C) {
  __shared__ float tile[32][33];
  const int bx = blockIdx.x * 32;  // C base
  const int by = blockIdx.y * 32;  // R base
  const int tx = threadIdx.x & 31, ty = threadIdx.x >> 5;
#pragma unroll
  for (int i = 0; i < 32; i += 8)
    tile[ty + i][tx] = in[(size_t)(by + ty + i) * C + (bx + tx)];
  __syncthreads();
#pragma unroll
  for (int i = 0; i < 32; i += 8)
    out[(size_t)(bx + ty + i) * R + (by + tx)] = (_Float16)tile[tx][ty + i];
}

extern "C" void kernel_launch(void* const* d_in, const int* in_sizes, int n_in,
                              void* d_out, int out_size, void* d_ws, size_t ws_size,
                              hipStream_t stream) {
  const float* x = (const float*)d_in[0];      // [16384][768]
  const float* w_qkv = (const float*)d_in[1];  // [768][2304]
  const float* b_qkv = (const float*)d_in[2];  // [2304]
  const float* w_out = (const float*)d_in[3];  // [768][768]
  const float* b_out = (const float*)d_in[4];  // [768]
  float* out = (float*)d_out;                  // [16384][768] — also used as
                                               // split-K f32 partial scratch
  char* ws = (char*)d_ws;

  // ws layout (peak identical to proven rounds).  Vth sits in the old Vh
  // slot (QKV writes V^T there directly; plain V is never materialized).
  // Ch overlays the same region: reduce_ctx(c) overwrites exactly Vth
  // batches {2c,2c+1}, which PV(c) has already fully consumed (stream order).
  _Float16* xh    = (_Float16*)(ws + 0);           // 25 MB  (dead after QKV gemm)
  _Float16* wqkvh = (_Float16*)(ws + 25165824);    // 3.5 MB [2304][768] = W^T
  _Float16* wouth = (_Float16*)(ws + 28704768);    // 1.2 MB [768][768]  = Wout^T
  _Float16* Qh    = (_Float16*)(ws + 29884416);    // 25 MB  (pre-scaled)
  _Float16* Kh    = (_Float16*)(ws + 55050240);    // 25 MB
  _Float16* Vth   = (_Float16*)(ws + 80216064);    // 25 MB [4][768][4096] V^T
  _Float16* Sh    = (_Float16*)(ws + 105381888);   // 64 MB  f16 scores, 2 batches
  _Float16* Ch    = (_Float16*)(ws + 80216064);    // overlays Vth (see above)

  const size_t zQK = (size_t)NN * DD;   // per-batch stride Q/K/Vt/C (f16 elems)
  const size_t zS = (size_t)NN * NN;    // per-batch stride S (f16 elems)
  const size_t zCtx = (size_t)NN * DD;  // per-batch stride ctx partial (f32)
  const size_t chalf = 2 * zCtx;        // k-half stride in d_out (f32 elems)

  // 1) precision converts / weight transposes
  cvt_f16<<<dim3((MTOT * DD / 4) / 256), 256, 0, stream>>>(x, xh, MTOT * DD / 4);
  transpose_cvt<<<dim3(EE / 32, DD / 32), 256, 0, stream>>>(w_qkv, wqkvh, DD, EE);
  transpose_cvt<<<dim3(DD / 32, DD / 32), 256, 0, stream>>>(w_out, wouth, DD, DD);

  // 2) fused QKV projection (scale folded into Q; V written TRANSPOSED):
  //    grid (64, 9)
  gemm256<EPI_QKV><<<dim3(MTOT / 256, EE / 256), 512, 0, stream>>>(
      xh, DD, 0, wqkvh, DD, 0, DD, nullptr, nullptr, 0, 0, 0, b_qkv, Qh, Kh,
      Vth);

  // 3) attention in 2-batch chunks: S=QK^T (f16) ; softmax ; ctx=PV split-K=2
  //    PV partials: plain f32 stores into the two halves of d_out (50.3 MB =
  //    exactly 2 halves x 2 batches x 4096 x 768 f32), then reduce to Ch f16.
  for (int c = 0; c < BB / 2; ++c) {
    const _Float16* Qc = Qh + (size_t)c * 2 * zQK;
    const _Float16* Kc = Kh + (size_t)c * 2 * zQK;
    const _Float16* Vtc = Vth + (size_t)c * 2 * zQK;
    gemm256<EPI_QKT, 1><<<dim3(NN / 256, NN / 256, 2), 512, 0, stream>>>(
        Qc, DD, zQK, Kc, DD, zQK, DD, nullptr, Sh, NN, zS, 0, nullptr, nullptr,
        nullptr, nullptr);
    softmax_rows_f16<<<dim3(NN, 2), 256, 0, stream>>>(Sh);
    gemm256<EPI_PV><<<dim3(NN / 256, DD / 256, 4), 512, 0, stream>>>(
        Sh, NN, zS, Vtc, NN, zQK, NN / 2, out, nullptr, DD, zCtx, chalf,
        nullptr, nullptr, nullptr, nullptr);
    reduce_ctx<<<dim3((int)(chalf / 4 / 256)), 256, 0, stream>>>(
        out, out + chalf, Ch + (size_t)c * 2 * zQK, (int)(chalf / 4));
  }

  // 4) output projection (reads Ch f16; overwrites d_out with final f32+bias)
  gemm256<EPI_OUT><<<dim3(MTOT / 256, DD / 256), 512, 0, stream>>>(
      Ch, DD, 0, wouth, DD, 0, DD, out, nullptr, DD, 0, 0, b_out, nullptr,
      nullptr, nullptr);
}